// Round 8
// baseline (501.479 us; speedup 1.0000x reference)
//
#include <hip/hip_runtime.h>
#include <hip/hip_bf16.h>
#include <math.h>

// Mamba block. 8 launches: prep(transposes+rmsnorm+zero) | in_proj gemm |
// x_proj gemm w/ conv+silu fused (split-K, atomicAdd) | dt gemm |
// scan part1/2/3 (conv fused via rolling window, 32 chunks) | out_proj gemm.
// Dims fixed: B=4, L=2048, dim=1024, d_inner=2048, d_state=16, d_conv=4,
// dt_rank=64. Rows = B*L = 8192.
//
// gemm_ring (this round): BK=64, ring-2. Rounds 0-5 showed per-K-tile cost
// is ~3300 cyc regardless of schedule (phases/prefetch/occupancy all null)
// — a fixed per-iteration overhead ~4x the pipe-busy time. So halve the
// iteration count: K-step 64, one barrier + one vmcnt(0) per 64 K-elements
// (was 3 barriers per 32). Fragment-major LDS, each K-tile = two 1 KiB
// k-half frags per 16-row group (DMA src offset +32 selects half; layout
// stays linear/conflict-free). Frags register-loaded per k-half so regs
// stay ~220 (2 waves/SIMD). Stage(t+1) at iter top = full-iter DMA lead.
// Scans: round-2 scalar build (round-6 vectorization measured null).

#define ROWS 8192
#define DIM 1024
#define DINNER 2048
#define DSTATE 16
#define DTRANK 64
#define LSEQ 2048
#define NCHUNK 32
#define LCHUNK 64    // LSEQ/NCHUNK

#define LOG2E 1.4426950408889634f

typedef unsigned short ushort;
typedef __attribute__((ext_vector_type(8))) short short8;
typedef __attribute__((ext_vector_type(4))) float float4v;

__device__ inline ushort f2bf(float f) {
    __hip_bfloat16 h = __float2bfloat16(f);
    return *reinterpret_cast<ushort*>(&h);
}
__device__ inline float bf2f(ushort u) {
    union { unsigned int i; float f; } w; w.i = ((unsigned int)u) << 16; return w.f;
}

// raw v_exp_f32 (2^x), single instruction. NOT libm exp2f (precise, ~6 instr).
__device__ inline float fexp2(float x) {
#if __has_builtin(__builtin_amdgcn_exp2f)
    return __builtin_amdgcn_exp2f(x);
#else
    return __expf(x * 0.69314718056f);
#endif
}

// async global->LDS DMA, 16 B/lane. lds dest = wave-uniform base + lane*16.
__device__ inline void dma16(const void* g, void* l) {
    __builtin_amdgcn_global_load_lds(
        (const __attribute__((address_space(1))) unsigned int*)g,
        (__attribute__((address_space(3))) unsigned int*)l, 16, 0, 0);
}

// counted vmcnt wait with literal N (compiler fence via "memory")
template <int N> __device__ inline void vwait() {
    if constexpr (N == 0)      asm volatile("s_waitcnt vmcnt(0)" ::: "memory");
    else if constexpr (N == 6) asm volatile("s_waitcnt vmcnt(6)" ::: "memory");
    else if constexpr (N == 8) asm volatile("s_waitcnt vmcnt(8)" ::: "memory");
    else static_assert(N < 0, "unsupported vmcnt literal");
}

// ---------------- fused prep: 4 transposes + RMSNorm + dbc zero ------------
__global__ __launch_bounds__(256)
void prep_kernel(const float* __restrict__ in_proj, ushort* __restrict__ bt1,
                 const float* __restrict__ out_proj, ushort* __restrict__ bt2,
                 const float* __restrict__ x_proj, ushort* __restrict__ bt3,
                 const float* __restrict__ dt_w, ushort* __restrict__ bt4,
                 const float* __restrict__ x, const float* __restrict__ rms_w,
                 ushort* __restrict__ xn, float* __restrict__ dbc) {
    __shared__ float tld[32][33];
    __shared__ float red[4];
    int bid = blockIdx.x, tid = threadIdx.x;
    if (bid < 6464) {
        const float* in; ushort* outT; int R, C, bx, by;
        if (bid < 4096)      { in = in_proj;  outT = bt1; R = 1024; C = 4096; bx = bid & 127; by = bid >> 7; }
        else if (bid < 6144) { int t = bid - 4096; in = out_proj; outT = bt2; R = 2048; C = 1024; bx = t & 31; by = t >> 5; }
        else if (bid < 6336) { int t = bid - 6144; in = x_proj;  outT = bt3; R = 2048; C = 96;  bx = t % 3;  by = t / 3; }
        else                 { int t = bid - 6336; in = dt_w;    outT = bt4; R = 64;   C = 2048; bx = t & 63; by = t >> 6; }
        int tx = tid & 31, ty = tid >> 5;
#pragma unroll
        for (int k = 0; k < 4; ++k)
            tld[ty + k * 8][tx] = in[(long)(by * 32 + ty + k * 8) * C + bx * 32 + tx];
        __syncthreads();
#pragma unroll
        for (int k = 0; k < 4; ++k)
            outT[(long)(bx * 32 + ty + k * 8) * R + by * 32 + tx] = f2bf(tld[tx][ty + k * 8]);
    } else if (bid < 14656) {
        int row = bid - 6464;
        float4 xv = ((const float4*)(x + (long)row * DIM))[tid];
        float ss = xv.x * xv.x + xv.y * xv.y + xv.z * xv.z + xv.w * xv.w;
        for (int off = 32; off > 0; off >>= 1) ss += __shfl_down(ss, off);
        if ((tid & 63) == 0) red[tid >> 6] = ss;
        __syncthreads();
        float scale = rsqrtf((red[0] + red[1] + red[2] + red[3]) / DIM + 1e-5f);
        float4 wv = ((const float4*)rms_w)[tid];
        ushort4 ov;
        ov.x = f2bf(xv.x * scale * wv.x);
        ov.y = f2bf(xv.y * scale * wv.y);
        ov.z = f2bf(xv.z * scale * wv.z);
        ov.w = f2bf(xv.w * scale * wv.w);
        ((ushort4*)xn)[(long)row * 256 + tid] = ov;
    } else {
        int idx = (bid - 14656) * 256 + tid;
        float4 z = {0.f, 0.f, 0.f, 0.f};
        ((float4*)dbc)[idx] = z;   // 768*256*4 = 786432 floats
    }
}

// ---------------- BK=64 ring-2 fragment-major MFMA GEMM --------------------
// MW x NW waves; per-wave output (MF*16) x (NF*16). K-step 64.
// LDS slot: A row-groups [BLKM/16] x 2 k-half frags (1 KiB each, MFMA lane
// order: lane l -> row l&15, kseg l>>4), then B likewise. DMA source offset
// +32 elems selects k-half -> dest stays linear (wave-uniform + lane*16).
// Ring-2: stage(t+1, s^1) at iter top (slot of t-1; its reads retired via
// the compiler's lgkm waits before the end-of-(t-1) barrier). One vmcnt(0)
// + one barrier per iteration.
// EPI: 0 = bf16 store; 2 = acc + aux[row*ldc+col] -> f32 (residual).
template <int MW, int NW, int MF, int NF, int EPI>
__global__ __launch_bounds__(MW * NW * 64, 2)
void gemm_ring(const ushort* __restrict__ A, int lda,
               const ushort* __restrict__ Bt, int ldbt,
               void* __restrict__ Cv, int ldc, int K,
               const float* __restrict__ aux) {
    constexpr int W    = MW * NW;             // waves per block (8)
    constexpr int BLKM = MW * MF * 16;
    constexpr int BLKN = NW * NF * 16;
    constexpr int TILE = (BLKM + BLKN) * 64;  // ushorts per ring slot
    constexpr int NA   = BLKM / (16 * W);     // A row-groups per wave
    constexpr int NB   = BLKN / (16 * W);     // B row-groups per wave
    __shared__ __align__(16) ushort lds[2 * TILE];

    const int tid  = threadIdx.x;
    const int w    = tid >> 6, lane = tid & 63;
    const int wm   = w / NW,   wn   = w % NW;
    const int quad = lane >> 4, l16 = lane & 15;
    const long row0 = (long)blockIdx.y * BLKM;
    const long col0 = (long)blockIdx.x * BLKN;

    // per-lane global sources in fragment order (row = l&15, kseg = l>>4)
    const ushort* gA[NA];
    const ushort* gB[NB];
#pragma unroll
    for (int i = 0; i < NA; ++i)
        gA[i] = A + (row0 + (w + i * W) * 16 + l16) * lda + quad * 8;
#pragma unroll
    for (int i = 0; i < NB; ++i)
        gB[i] = Bt + (col0 + (w + i * W) * 16 + l16) * ldbt + quad * 8;

    const int NT = K >> 6;                    // K-tiles of 64
    float4v acc[MF][NF] = {};

    auto stage = [&](int kt, int slot) {
        ushort* lb  = lds + slot * TILE;
        ushort* lbB = lb + BLKM * 64;
        const int ko = kt << 6;
#pragma unroll
        for (int i = 0; i < NA; ++i) {
            dma16(gA[i] + ko,      lb + ((w + i * W) * 2 + 0) * 512);
            dma16(gA[i] + ko + 32, lb + ((w + i * W) * 2 + 1) * 512);
        }
#pragma unroll
        for (int i = 0; i < NB; ++i) {
            dma16(gB[i] + ko,      lbB + ((w + i * W) * 2 + 0) * 512);
            dma16(gB[i] + ko + 32, lbB + ((w + i * W) * 2 + 1) * 512);
        }
    };

    stage(0, 0);
    vwait<0>();
    __builtin_amdgcn_s_barrier();

    for (int t = 0; t < NT; ++t) {
        const int s = t & 1;
        if (t + 1 < NT) stage(t + 1, s ^ 1);   // full-iteration DMA lead
        const ushort* lb  = lds + s * TILE;
        const ushort* lbB = lb + BLKM * 64;
#pragma unroll
        for (int h = 0; h < 2; ++h) {          // two k-halves, regs reused
            short8 af[MF], bfr[NF];
#pragma unroll
            for (int m = 0; m < MF; ++m)
                af[m] = *reinterpret_cast<const short8*>(
                    &lb[((wm * MF + m) * 2 + h) * 512 + lane * 8]);
#pragma unroll
            for (int n = 0; n < NF; ++n)
                bfr[n] = *reinterpret_cast<const short8*>(
                    &lbB[((wn * NF + n) * 2 + h) * 512 + lane * 8]);
#pragma unroll
            for (int m = 0; m < MF; ++m)
#pragma unroll
                for (int n = 0; n < NF; ++n)
                    acc[m][n] = __builtin_amdgcn_mfma_f32_16x16x32_bf16(
                        af[m], bfr[n], acc[m][n], 0, 0, 0);
        }
        vwait<0>();                            // drain stage(t+1)
        if (t < NT - 1) __builtin_amdgcn_s_barrier();
    }

#pragma unroll
    for (int m = 0; m < MF; ++m) {
#pragma unroll
        for (int n = 0; n < NF; ++n) {
            long rbase = row0 + wm * (MF * 16) + m * 16 + quad * 4;
            long c = col0 + wn * (NF * 16) + n * 16 + l16;
#pragma unroll
            for (int r = 0; r < 4; ++r) {
                float v = acc[m][n][r];
                long idx = (rbase + r) * (long)ldc + c;
                if (EPI == 2) ((float*)Cv)[idx] = v + aux[idx];
                else          ((ushort*)Cv)[idx] = f2bf(v);
            }
        }
    }
}

// ------- x_proj GEMM with conv+silu fused into A-staging, split-K ----------
__global__ __launch_bounds__(256)
void xproj_conv_gemm(const ushort* __restrict__ xz,
                     const float* __restrict__ cw, const float* __restrict__ cb,
                     const ushort* __restrict__ bt3,   // [128][2048]
                     float* __restrict__ dbc) {
    __shared__ __align__(16) ushort As[128][32];
    __shared__ __align__(16) ushort Bs[128][32];
    int tid = threadIdx.x;
    int wave = tid >> 6, lane = tid & 63;
    int wm = wave >> 1, wn = wave & 1;
    int quad = lane >> 4, l16 = lane & 15;
    int row0 = blockIdx.y * 128;
    int ks0 = blockIdx.x * 512;
    int srow = tid >> 2, sseg = tid & 3;

    int r0 = (wave * 2 + 0) * 16 + (lane >> 2);
    int r1 = (wave * 2 + 1) * 16 + (lane >> 2);
    int ksl = (lane & 3) * 8;
    const ushort* b0 = bt3 + (long)r0 * 2048 + ks0 + ksl;
    const ushort* b1 = bt3 + (long)r1 * 2048 + ks0 + ksl;
    ushort* lB0 = &Bs[(wave * 2 + 0) * 16][0];
    ushort* lB1 = &Bs[(wave * 2 + 1) * 16][0];

    float4v acc[4][4] = {};

    for (int k0 = 0; k0 < 512; k0 += 32) {
        dma16(b0 + k0, lB0);
        dma16(b1 + k0, lB1);
#pragma unroll
        for (int it = 0; it < 2; ++it) {
            int r = srow + it * 64;
            long row = row0 + r;
            int l = (int)(row & (LSEQ - 1));
            int cch = ks0 + k0 + sseg * 8;
            short8 v[4];
#pragma unroll
            for (int t = 0; t < 4; ++t) {
                if (l - 3 + t >= 0) v[t] = *(const short8*)&xz[(row - 3 + t) * 4096 + cch];
                else { short8 zz = {0,0,0,0,0,0,0,0}; v[t] = zz; }
            }
            ushort o[8];
#pragma unroll
            for (int j = 0; j < 8; ++j) {
                float4 w = ((const float4*)cw)[cch + j];
                float a = cb[cch + j]
                        + bf2f((ushort)v[0][j]) * w.x + bf2f((ushort)v[1][j]) * w.y
                        + bf2f((ushort)v[2][j]) * w.z + bf2f((ushort)v[3][j]) * w.w;
                a = a / (1.f + __expf(-a));
                o[j] = f2bf(a);
            }
            *(short8*)&As[r][sseg * 8] = *(const short8*)o;
        }
        __syncthreads();

        short8 afrag[4], bfrag[4];
#pragma unroll
        for (int i = 0; i < 4; ++i)
            afrag[i] = *reinterpret_cast<const short8*>(&As[wm * 64 + i * 16 + l16][quad * 8]);
#pragma unroll
        for (int j = 0; j < 4; ++j)
            bfrag[j] = *reinterpret_cast<const short8*>(&Bs[wn * 64 + j * 16 + l16][quad * 8]);
#pragma unroll
        for (int i = 0; i < 4; ++i)
#pragma unroll
            for (int j = 0; j < 4; ++j)
                acc[i][j] = __builtin_amdgcn_mfma_f32_16x16x32_bf16(
                    afrag[i], bfrag[j], acc[i][j], 0, 0, 0);
        __syncthreads();
    }
#pragma unroll
    for (int i = 0; i < 4; ++i) {
#pragma unroll
        for (int j = 0; j < 4; ++j) {
            int rbase = row0 + wm * 64 + i * 16 + quad * 4;
            int c = wn * 64 + j * 16 + l16;
            if (c < 96) {
#pragma unroll
                for (int r = 0; r < 4; ++r)
                    atomicAdd(&dbc[(long)(rbase + r) * 96 + c], acc[i][j][r]);
            }
        }
    }
}

// ---------------- VALU-staged MFMA GEMM for dt (A fp32, K=64) ----------------
__global__ __launch_bounds__(256)
void mfma_gemm_dt(const float* __restrict__ A, int lda,
                  const ushort* __restrict__ Bt, int ldbt,
                  ushort* __restrict__ C, int ldc, int K,
                  const float* __restrict__ aux) {
    __shared__ __align__(16) ushort As[128][40];
    __shared__ __align__(16) ushort Bs[128][40];
    int tid = threadIdx.x;
    int wave = tid >> 6, lane = tid & 63;
    int wm = wave >> 1, wn = wave & 1;
    int quad = lane >> 4, l16 = lane & 15;
    int row0 = blockIdx.y * 128, col0 = blockIdx.x * 128;
    int srow = tid >> 2, sseg = tid & 3;

    float4v acc[4][4] = {};

    for (int k0 = 0; k0 < K; k0 += 32) {
#pragma unroll
        for (int it = 0; it < 2; ++it) {
            int r = srow + it * 64;
            const float* ap = A + (long)(row0 + r) * lda + k0 + sseg * 8;
            ushort tmp[8];
#pragma unroll
            for (int j = 0; j < 8; ++j) tmp[j] = f2bf(ap[j]);
            *reinterpret_cast<short8*>(&As[r][sseg * 8]) =
                *reinterpret_cast<const short8*>(tmp);
            const ushort* bp = Bt + (long)(col0 + r) * ldbt + k0 + sseg * 8;
            *reinterpret_cast<short8*>(&Bs[r][sseg * 8]) =
                *reinterpret_cast<const short8*>(bp);
        }
        __syncthreads();
        short8 afrag[4], bfrag[4];
#pragma unroll
        for (int i = 0; i < 4; ++i)
            afrag[i] = *reinterpret_cast<const short8*>(&As[wm * 64 + i * 16 + l16][quad * 8]);
#pragma unroll
        for (int j = 0; j < 4; ++j)
            bfrag[j] = *reinterpret_cast<const short8*>(&Bs[wn * 64 + j * 16 + l16][quad * 8]);
#pragma unroll
        for (int i = 0; i < 4; ++i)
#pragma unroll
            for (int j = 0; j < 4; ++j)
                acc[i][j] = __builtin_amdgcn_mfma_f32_16x16x32_bf16(
                    afrag[i], bfrag[j], acc[i][j], 0, 0, 0);
        __syncthreads();
    }
#pragma unroll
    for (int i = 0; i < 4; ++i) {
#pragma unroll
        for (int j = 0; j < 4; ++j) {
            int rbase = row0 + wm * 64 + i * 16 + quad * 4;
            int c = col0 + wn * 64 + j * 16 + l16;
#pragma unroll
            for (int r = 0; r < 4; ++r) {
                float v = acc[i][j][r] + aux[c];
                v = (v > 20.f) ? v : __logf(1.f + __expf(v));
                C[(long)(rbase + r) * ldc + c] = f2bf(v);
            }
        }
    }
}

// ---------------- chunked selective scan, conv fused -----------------------
// thread = (b,c); 32 chunks of 64. A2[s] = A*log2(e); decay = v_exp(d*A2).
__global__ __launch_bounds__(256)
void scan_part1(const ushort* __restrict__ xz,     // xi at row*4096 + c
                const ushort* __restrict__ dlt,    // delta [8192][2048]
                const float* __restrict__ dbc,     // [ROWS][96]: dt|B|C
                const float* __restrict__ A_log,
                const float* __restrict__ cw, const float* __restrict__ cb,
                float* __restrict__ hbuf,          // [B][G][16][2048]
                float* __restrict__ sdbuf) {       // [B][G][2048]
    int c = blockIdx.y * 256 + threadIdx.x;
    int b = blockIdx.z, g = blockIdx.x;
    float A2[16];
#pragma unroll
    for (int s = 0; s < 16; ++s) A2[s] = -__expf(A_log[c * 16 + s]) * LOG2E;
    float4 w = ((const float4*)cw)[c];
    float cbc = cb[c];
    float h[16] = {};
    float sumd = 0.f;
    long row0 = (long)b * LSEQ + (long)g * LCHUNK;
    int l0 = g * LCHUNK;
    float x0 = (l0 >= 3) ? bf2f(xz[(row0 - 3) * 4096 + c]) : 0.f;
    float x1 = (l0 >= 2) ? bf2f(xz[(row0 - 2) * 4096 + c]) : 0.f;
    float x2 = (l0 >= 1) ? bf2f(xz[(row0 - 1) * 4096 + c]) : 0.f;
    long row = row0;
    for (int l = 0; l < LCHUNK; ++l, ++row) {
        float x3 = bf2f(xz[row * 4096 + c]);
        float xc = cbc + x0 * w.x + x1 * w.y + x2 * w.z + x3 * w.w;
        xc = xc / (1.f + __expf(-xc));
        x0 = x1; x1 = x2; x2 = x3;
        float d = bf2f(dlt[row * 2048 + c]);
        const float* __restrict__ bc = dbc + row * 96;
        sumd += d;
        float dx = d * xc;
#pragma unroll
        for (int s = 0; s < 16; ++s)
            h[s] = fexp2(d * A2[s]) * h[s] + dx * bc[64 + s];
    }
    long hb = ((long)(b * NCHUNK + g) * 16) * 2048 + c;
#pragma unroll
    for (int s = 0; s < 16; ++s) hbuf[hb + (long)s * 2048] = h[s];
    sdbuf[(long)(b * NCHUNK + g) * 2048 + c] = sumd;
}

// part2: serial combine over chunks; hbuf becomes h_in per chunk.
__global__ __launch_bounds__(256)
void scan_part2(float* __restrict__ hbuf, const float* __restrict__ sdbuf,
                const float* __restrict__ A_log) {
    int gl = blockIdx.x * 256 + threadIdx.x;   // 131072 threads
    int c = gl & 2047, s = (gl >> 11) & 15, b = gl >> 15;
    float A2 = -__expf(A_log[c * 16 + s]) * LOG2E;
    float hrun = 0.f;
    for (int g = 0; g < NCHUNK; ++g) {
        long hi = ((long)(b * NCHUNK + g) * 16 + s) * 2048 + c;
        float hout = hbuf[hi];
        float sd = sdbuf[(long)(b * NCHUNK + g) * 2048 + c];
        hbuf[hi] = hrun;
        hrun = fexp2(A2 * sd) * hrun + hout;
    }
}

// part3: re-scan from h_in; y = sum_s h*C; D-skip + SiLU gate; y -> dlt (bf16).
__global__ __launch_bounds__(256)
void scan_part3(const ushort* __restrict__ xz,    // xi + z halves (read-only)
                ushort* __restrict__ dlt,         // delta in / gated y out
                const float* __restrict__ dbc,
                const float* __restrict__ A_log,
                const float* __restrict__ cw, const float* __restrict__ cb,
                const float* __restrict__ Dp,
                const float* __restrict__ hbuf) {
    int c = blockIdx.y * 256 + threadIdx.x;
    int b = blockIdx.z, g = blockIdx.x;
    float A2[16], h[16];
#pragma unroll
    for (int s = 0; s < 16; ++s) A2[s] = -__expf(A_log[c * 16 + s]) * LOG2E;
    long hb = ((long)(b * NCHUNK + g) * 16) * 2048 + c;
#pragma unroll
    for (int s = 0; s < 16; ++s) h[s] = hbuf[hb + (long)s * 2048];
    float4 w = ((const float4*)cw)[c];
    float cbc = cb[c];
    float Dc = Dp[c];
    long row0 = (long)b * LSEQ + (long)g * LCHUNK;
    int l0 = g * LCHUNK;
    float x0 = (l0 >= 3) ? bf2f(xz[(row0 - 3) * 4096 + c]) : 0.f;
    float x1 = (l0 >= 2) ? bf2f(xz[(row0 - 2) * 4096 + c]) : 0.f;
    float x2 = (l0 >= 1) ? bf2f(xz[(row0 - 1) * 4096 + c]) : 0.f;
    long row = row0;
    for (int l = 0; l < LCHUNK; ++l, ++row) {
        float x3 = bf2f(xz[row * 4096 + c]);
        float xc = cbc + x0 * w.x + x1 * w.y + x2 * w.z + x3 * w.w;
        xc = xc / (1.f + __expf(-xc));
        x0 = x1; x1 = x2; x2 = x3;
        float d = bf2f(dlt[row * 2048 + c]);
        float z = bf2f(xz[row * 4096 + 2048 + c]);
        const float* __restrict__ bc = dbc + row * 96;
        float dx = d * xc;
        float y = 0.f;
#pragma unroll
        for (int s = 0; s < 16; ++s) {
            h[s] = fexp2(d * A2[s]) * h[s] + dx * bc[64 + s];
            y += h[s] * bc[80 + s];
        }
        float yv = (y + xc * Dc) * (z / (1.f + __expf(-z)));
        dlt[row * 2048 + c] = f2bf(yv);
    }
}

extern "C" void kernel_launch(void* const* d_in, const int* in_sizes, int n_in,
                              void* d_out, int out_size, void* d_ws, size_t ws_size,
                              hipStream_t stream) {
    const float* x        = (const float*)d_in[0];
    const float* rms_w    = (const float*)d_in[1];
    const float* in_proj  = (const float*)d_in[2];
    const float* conv_w   = (const float*)d_in[3];
    const float* conv_b   = (const float*)d_in[4];
    const float* x_proj   = (const float*)d_in[5];
    const float* dt_w     = (const float*)d_in[6];
    const float* dt_b     = (const float*)d_in[7];
    const float* A_log    = (const float*)d_in[8];
    const float* Dp       = (const float*)d_in[9];
    const float* out_proj = (const float*)d_in[10];
    float* out = (float*)d_out;

    char* p = (char*)d_ws;
    ushort* xz  = (ushort*)p;   p += (size_t)ROWS * 4096 * 2;   // 64 MB  xi|z
    ushort* dlt = (ushort*)p;   p += (size_t)ROWS * 2048 * 2;   // 32 MB  delta -> gated y
    float*  dbc = (float*)p;    p += (size_t)ROWS * 96 * 4;     // 3 MB
    ushort* bt1 = (ushort*)p;   p += (size_t)4096 * 1024 * 2;   // 8 MB   in_proj^T
    ushort* bt2 = (ushort*)p;   p += (size_t)1024 * 2048 * 2;   // 4 MB   out_proj^T
    ushort* bt3 = (ushort*)p;   p += (size_t)128 * 2048 * 2;    // 512 KB x_proj^T (96 rows valid)
    ushort* bt4 = (ushort*)p;   p += (size_t)2048 * 64 * 2;     // 256 KB dt_w^T
    ushort* xn  = (ushort*)p;   p += (size_t)ROWS * 1024 * 2;   // 16.78 MB (dead after in_proj)
    float* sdbuf = (float*)p;   p += (size_t)4 * NCHUNK * 2048 * 4; // 1 MB
    float* hbuf  = (float*)xn;  // 4*32*16*2048*4 = 16.78 MB, overlays xn exactly
    // total ~129 MiB

    // 1. prep: weight transposes + RMSNorm -> xn bf16 + dbc zero
    prep_kernel<<<15424, 256, 0, stream>>>(in_proj, bt1, out_proj, bt2,
                                           x_proj, bt3, dt_w, bt4,
                                           x, rms_w, xn, dbc);
    // 2. xz = xn @ in_proj  [8192,1024]@[1024,4096] -> bf16
    //    256x256 tile, 8 waves, BK=64 ring-2 (128 KiB): grid 16x32, 16 iters.
    gemm_ring<2, 4, 8, 4, 0><<<dim3(4096 / 256, ROWS / 256), 512, 0, stream>>>(
        xn, DIM, bt1, 1024, xz, 4096, DIM, nullptr);
    // 3. dbc += silu(conv(xi)) @ x_proj  (fused conv, split-K x4, atomics)
    xproj_conv_gemm<<<dim3(4, ROWS / 128), 256, 0, stream>>>(
        xz, conv_w, conv_b, bt3, dbc);
    // 4. dlt = softplus(dbc[:,:64] @ dt_w + dt_b) -> bf16
    mfma_gemm_dt<<<dim3(2048 / 128, ROWS / 128), 256, 0, stream>>>(
        dbc, 96, bt4, 64, dlt, 2048, DTRANK, dt_b);
    // 5-7. chunked selective scan (conv recomputed via rolling window)
    scan_part1<<<dim3(NCHUNK, DINNER / 256, 4), 256, 0, stream>>>(
        xz, dlt, dbc, A_log, conv_w, conv_b, hbuf, sdbuf);
    scan_part2<<<512, 256, 0, stream>>>(hbuf, sdbuf, A_log);
    scan_part3<<<dim3(NCHUNK, DINNER / 256, 4), 256, 0, stream>>>(
        xz, dlt, dbc, A_log, conv_w, conv_b, Dp, hbuf);
    // 8. out = x + y @ out_proj  [8192,2048]@[2048,1024] -> f32 (residual)
    //    256x128 tile, 8 waves, BK=64 ring-2 (96 KiB): grid 8x32, 32 iters.
    gemm_ring<4, 2, 4, 4, 2><<<dim3(DIM / 128, ROWS / 256), 512, 0, stream>>>(
        dlt, DINNER, bt2, DINNER, out, DIM, DINNER, x);
}

// Round 9
// 476.573 us; speedup vs baseline: 1.0523x; 1.0523x over previous
//
#include <hip/hip_runtime.h>
#include <hip/hip_bf16.h>
#include <math.h>

// Mamba block. 8 launches: prep(transposes+rmsnorm+zero) | in_proj gemm |
// x_proj gemm w/ conv+silu fused (split-K, atomicAdd) | dt gemm |
// scan part1/2/3 (conv fused via rolling window, 32 chunks) | out_proj gemm.
// Dims fixed: B=4, L=2048, dim=1024, d_inner=2048, d_state=16, d_conv=4,
// dt_rank=64. Rows = B*L = 8192.
//
// gemm_ring (this round): m201-style QUADRANT PHASES on fragment-major LDS.
// Prior 7 rounds: coarse phase-splits / occupancy / ring-depth / BK all
// null-to-negative (m196: coarse split without fine interleave HURTS).
// Faithful structure: BK=64, 2 buffers; per K-tile 4 phases, each phase
// {ds_read only the register subtile this phase's 16 MFMAs need; stage a
// fraction of tile t+2; barrier; lgkmcnt(0); setprio(1); 16 MFMA;
// setprio(0); barrier}. A/B register sets reused across phases (B0 lives
// P1->P4). Staging placed where WAR-safe with 2 buffers: B of t+2 in P3
// (all B reads retired at P2 post-barrier), A of t+2 in P4 (A retired at
// P3 post-barrier). One counted vmcnt(DPT) + barrier per K-tile at iter
// end (never 0 mid-loop). Fragment-major: frag (group g, khalf h) at
// (g*2+h)*1KiB in lane order -> ds_read_b128 at lane*16, 0 conflicts;
// per-lane global src pre-permuted (row=l&15, kseg=quad).

#define ROWS 8192
#define DIM 1024
#define DINNER 2048
#define DSTATE 16
#define DTRANK 64
#define LSEQ 2048
#define NCHUNK 32
#define LCHUNK 64    // LSEQ/NCHUNK

#define LOG2E 1.4426950408889634f

typedef unsigned short ushort;
typedef __attribute__((ext_vector_type(8))) short short8;
typedef __attribute__((ext_vector_type(4))) float float4v;

__device__ inline ushort f2bf(float f) {
    __hip_bfloat16 h = __float2bfloat16(f);
    return *reinterpret_cast<ushort*>(&h);
}
__device__ inline float bf2f(ushort u) {
    union { unsigned int i; float f; } w; w.i = ((unsigned int)u) << 16; return w.f;
}

// raw v_exp_f32 (2^x), single instruction. NOT libm exp2f (precise, ~6 instr).
__device__ inline float fexp2(float x) {
#if __has_builtin(__builtin_amdgcn_exp2f)
    return __builtin_amdgcn_exp2f(x);
#else
    return __expf(x * 0.69314718056f);
#endif
}

// async global->LDS DMA, 16 B/lane. lds dest = wave-uniform base + lane*16.
__device__ inline void dma16(const void* g, void* l) {
    __builtin_amdgcn_global_load_lds(
        (const __attribute__((address_space(1))) unsigned int*)g,
        (__attribute__((address_space(3))) unsigned int*)l, 16, 0, 0);
}

// counted vmcnt wait with literal N (compiler fence via "memory")
template <int N> __device__ inline void vwait() {
    if constexpr (N == 0)      asm volatile("s_waitcnt vmcnt(0)" ::: "memory");
    else if constexpr (N == 6) asm volatile("s_waitcnt vmcnt(6)" ::: "memory");
    else if constexpr (N == 8) asm volatile("s_waitcnt vmcnt(8)" ::: "memory");
    else static_assert(N < 0, "unsupported vmcnt literal");
}

__device__ inline void phase_sync_pre() {
    __builtin_amdgcn_s_barrier();
    asm volatile("s_waitcnt lgkmcnt(0)" ::: "memory");
    __builtin_amdgcn_sched_barrier(0);
    __builtin_amdgcn_s_setprio(1);
}
__device__ inline void phase_sync_post() {
    __builtin_amdgcn_s_setprio(0);
    __builtin_amdgcn_s_barrier();
}

// ---------------- fused prep: 4 transposes + RMSNorm + dbc zero ------------
__global__ __launch_bounds__(256)
void prep_kernel(const float* __restrict__ in_proj, ushort* __restrict__ bt1,
                 const float* __restrict__ out_proj, ushort* __restrict__ bt2,
                 const float* __restrict__ x_proj, ushort* __restrict__ bt3,
                 const float* __restrict__ dt_w, ushort* __restrict__ bt4,
                 const float* __restrict__ x, const float* __restrict__ rms_w,
                 ushort* __restrict__ xn, float* __restrict__ dbc) {
    __shared__ float tld[32][33];
    __shared__ float red[4];
    int bid = blockIdx.x, tid = threadIdx.x;
    if (bid < 6464) {
        const float* in; ushort* outT; int R, C, bx, by;
        if (bid < 4096)      { in = in_proj;  outT = bt1; R = 1024; C = 4096; bx = bid & 127; by = bid >> 7; }
        else if (bid < 6144) { int t = bid - 4096; in = out_proj; outT = bt2; R = 2048; C = 1024; bx = t & 31; by = t >> 5; }
        else if (bid < 6336) { int t = bid - 6144; in = x_proj;  outT = bt3; R = 2048; C = 96;  bx = t % 3;  by = t / 3; }
        else                 { int t = bid - 6336; in = dt_w;    outT = bt4; R = 64;   C = 2048; bx = t & 63; by = t >> 6; }
        int tx = tid & 31, ty = tid >> 5;
#pragma unroll
        for (int k = 0; k < 4; ++k)
            tld[ty + k * 8][tx] = in[(long)(by * 32 + ty + k * 8) * C + bx * 32 + tx];
        __syncthreads();
#pragma unroll
        for (int k = 0; k < 4; ++k)
            outT[(long)(bx * 32 + ty + k * 8) * R + by * 32 + tx] = f2bf(tld[tx][ty + k * 8]);
    } else if (bid < 14656) {
        int row = bid - 6464;
        float4 xv = ((const float4*)(x + (long)row * DIM))[tid];
        float ss = xv.x * xv.x + xv.y * xv.y + xv.z * xv.z + xv.w * xv.w;
        for (int off = 32; off > 0; off >>= 1) ss += __shfl_down(ss, off);
        if ((tid & 63) == 0) red[tid >> 6] = ss;
        __syncthreads();
        float scale = rsqrtf((red[0] + red[1] + red[2] + red[3]) / DIM + 1e-5f);
        float4 wv = ((const float4*)rms_w)[tid];
        ushort4 ov;
        ov.x = f2bf(xv.x * scale * wv.x);
        ov.y = f2bf(xv.y * scale * wv.y);
        ov.z = f2bf(xv.z * scale * wv.z);
        ov.w = f2bf(xv.w * scale * wv.w);
        ((ushort4*)xn)[(long)row * 256 + tid] = ov;
    } else {
        int idx = (bid - 14656) * 256 + tid;
        float4 z = {0.f, 0.f, 0.f, 0.f};
        ((float4*)dbc)[idx] = z;   // 768*256*4 = 786432 floats
    }
}

// ---------- BK=64 double-buffer quadrant-phase fragment-major GEMM ----------
// MW x NW waves; per-wave output (MF*16) x (NF*16). MH=MF/2, NH=NF/2.
// LDS buffer: A frags [(BLKM/16) groups x 2 khalves x 1KiB] then B likewise.
// Per K-tile t (buf t&1), 4 phases (quadrants over full K=64):
//  P1: read A-set0(MH*2) + B-set0(NH*2)          -> MFMA Q(lo m, lo n)
//  P2: read B-set1(NH*2)                          -> MFMA Q(lo m, hi n)
//  P3: read A-set1(MH*2); stage B frags of t+2    -> MFMA Q(hi m, hi n)
//  P4: stage A frags of t+2                       -> MFMA Q(hi m, lo n)
// Iter end: vmcnt(DPT) [t+2 in flight, t+1 landed] + barrier.
// EPI: 0 = bf16 store; 2 = acc + aux[row*ldc+col] -> f32 (residual).
template <int MW, int NW, int MF, int NF, int EPI>
__global__ __launch_bounds__(MW * NW * 64, 2)
void gemm_ring(const ushort* __restrict__ A, int lda,
               const ushort* __restrict__ Bt, int ldbt,
               void* __restrict__ Cv, int ldc, int K,
               const float* __restrict__ aux) {
    constexpr int W    = MW * NW;             // waves per block (8)
    constexpr int BLKM = MW * MF * 16;
    constexpr int BLKN = NW * NF * 16;
    constexpr int TILE = (BLKM + BLKN) * 64;  // ushorts per buffer
    constexpr int NAf  = BLKM / (8 * W);      // A frags staged per wave
    constexpr int NBf  = BLKN / (8 * W);      // B frags staged per wave
    constexpr int DPT  = NAf + NBf;           // dmas per wave per K-tile
    constexpr int MH   = MF / 2;
    constexpr int NH   = NF / 2;
    __shared__ __align__(16) ushort lds[2 * TILE];

    const int tid  = threadIdx.x;
    const int w    = tid >> 6, lane = tid & 63;
    const int wm   = w / NW,   wn   = w % NW;
    const int quad = lane >> 4, l16 = lane & 15;
    const long row0 = (long)blockIdx.y * BLKM;
    const long col0 = (long)blockIdx.x * BLKN;

    // per-lane global srcs in fragment order: frag f=(g,h): row g*16+l16,
    // k offset h*32 + quad*8. Wave w stages frags {w + i*W}.
    const ushort* gA[NAf];
    const ushort* gB[NBf];
#pragma unroll
    for (int i = 0; i < NAf; ++i) {
        int f = w + i * W;
        gA[i] = A + (row0 + (f >> 1) * 16 + l16) * lda + (f & 1) * 32 + quad * 8;
    }
#pragma unroll
    for (int i = 0; i < NBf; ++i) {
        int f = w + i * W;
        gB[i] = Bt + (col0 + (f >> 1) * 16 + l16) * ldbt + (f & 1) * 32 + quad * 8;
    }

    const int NT = K >> 6;                    // K-tiles of 64
    float4v acc[MF][NF] = {};

    auto stageA = [&](int kt) {
        ushort* lb = lds + (kt & 1) * TILE;
        const int ko = kt << 6;
#pragma unroll
        for (int i = 0; i < NAf; ++i)
            dma16(gA[i] + ko, lb + (w + i * W) * 512);
    };
    auto stageB = [&](int kt) {
        ushort* lb = lds + (kt & 1) * TILE + BLKM * 64;
        const int ko = kt << 6;
#pragma unroll
        for (int i = 0; i < NBf; ++i)
            dma16(gB[i] + ko, lb + (w + i * W) * 512);
    };

    // prologue: tiles 0,1 staged; tile 0 landed (tile 1's DPT may remain)
    stageB(0); stageA(0); stageB(1); stageA(1);
    vwait<DPT>();
    __builtin_amdgcn_s_barrier();

    for (int t = 0; t < NT; ++t) {
        const ushort* lb  = lds + (t & 1) * TILE;
        const ushort* lbB = lb + BLKM * 64;
        const bool stg = (t + 2 < NT);
        short8 A0[MH][2], A1[MH][2], B0[NH][2], B1[NH][2];

        // ---- P1: A-set0 + B-set0 -> Q(lo,lo) ----
#pragma unroll
        for (int m = 0; m < MH; ++m)
#pragma unroll
            for (int h = 0; h < 2; ++h)
                A0[m][h] = *reinterpret_cast<const short8*>(
                    &lb[((wm * MF + m) * 2 + h) * 512 + lane * 8]);
#pragma unroll
        for (int n = 0; n < NH; ++n)
#pragma unroll
            for (int h = 0; h < 2; ++h)
                B0[n][h] = *reinterpret_cast<const short8*>(
                    &lbB[((wn * NF + n) * 2 + h) * 512 + lane * 8]);
        phase_sync_pre();
#pragma unroll
        for (int m = 0; m < MH; ++m)
#pragma unroll
            for (int n = 0; n < NH; ++n)
#pragma unroll
                for (int h = 0; h < 2; ++h)
                    acc[m][n] = __builtin_amdgcn_mfma_f32_16x16x32_bf16(
                        A0[m][h], B0[n][h], acc[m][n], 0, 0, 0);
        phase_sync_post();

        // ---- P2: B-set1 -> Q(lo,hi) ----
#pragma unroll
        for (int n = 0; n < NH; ++n)
#pragma unroll
            for (int h = 0; h < 2; ++h)
                B1[n][h] = *reinterpret_cast<const short8*>(
                    &lbB[((wn * NF + NH + n) * 2 + h) * 512 + lane * 8]);
        phase_sync_pre();
#pragma unroll
        for (int m = 0; m < MH; ++m)
#pragma unroll
            for (int n = 0; n < NH; ++n)
#pragma unroll
                for (int h = 0; h < 2; ++h)
                    acc[m][NH + n] = __builtin_amdgcn_mfma_f32_16x16x32_bf16(
                        A0[m][h], B1[n][h], acc[m][NH + n], 0, 0, 0);
        phase_sync_post();

        // ---- P3: A-set1; stage B(t+2) [B reads retired at P2 post-bar] ----
#pragma unroll
        for (int m = 0; m < MH; ++m)
#pragma unroll
            for (int h = 0; h < 2; ++h)
                A1[m][h] = *reinterpret_cast<const short8*>(
                    &lb[((wm * MF + MH + m) * 2 + h) * 512 + lane * 8]);
        if (stg) stageB(t + 2);
        phase_sync_pre();
#pragma unroll
        for (int m = 0; m < MH; ++m)
#pragma unroll
            for (int n = 0; n < NH; ++n)
#pragma unroll
                for (int h = 0; h < 2; ++h)
                    acc[MH + m][NH + n] = __builtin_amdgcn_mfma_f32_16x16x32_bf16(
                        A1[m][h], B1[n][h], acc[MH + m][NH + n], 0, 0, 0);
        phase_sync_post();

        // ---- P4: stage A(t+2) [A reads retired at P3 post-bar] ----
        if (stg) stageA(t + 2);
        phase_sync_pre();
#pragma unroll
        for (int m = 0; m < MH; ++m)
#pragma unroll
            for (int n = 0; n < NH; ++n)
#pragma unroll
                for (int h = 0; h < 2; ++h)
                    acc[MH + m][n] = __builtin_amdgcn_mfma_f32_16x16x32_bf16(
                        A1[m][h], B0[n][h], acc[MH + m][n], 0, 0, 0);
        __builtin_amdgcn_s_setprio(0);

        // iteration end: t+1 must be landed before next iter's reads
        if (stg) vwait<DPT>(); else vwait<0>();
        if (t < NT - 1) __builtin_amdgcn_s_barrier();
    }

#pragma unroll
    for (int m = 0; m < MF; ++m) {
#pragma unroll
        for (int n = 0; n < NF; ++n) {
            long rbase = row0 + wm * (MF * 16) + m * 16 + quad * 4;
            long c = col0 + wn * (NF * 16) + n * 16 + l16;
#pragma unroll
            for (int r = 0; r < 4; ++r) {
                float v = acc[m][n][r];
                long idx = (rbase + r) * (long)ldc + c;
                if (EPI == 2) ((float*)Cv)[idx] = v + aux[idx];
                else          ((ushort*)Cv)[idx] = f2bf(v);
            }
        }
    }
}

// ------- x_proj GEMM with conv+silu fused into A-staging, split-K ----------
__global__ __launch_bounds__(256)
void xproj_conv_gemm(const ushort* __restrict__ xz,
                     const float* __restrict__ cw, const float* __restrict__ cb,
                     const ushort* __restrict__ bt3,   // [128][2048]
                     float* __restrict__ dbc) {
    __shared__ __align__(16) ushort As[128][32];
    __shared__ __align__(16) ushort Bs[128][32];
    int tid = threadIdx.x;
    int wave = tid >> 6, lane = tid & 63;
    int wm = wave >> 1, wn = wave & 1;
    int quad = lane >> 4, l16 = lane & 15;
    int row0 = blockIdx.y * 128;
    int ks0 = blockIdx.x * 512;
    int srow = tid >> 2, sseg = tid & 3;

    int r0 = (wave * 2 + 0) * 16 + (lane >> 2);
    int r1 = (wave * 2 + 1) * 16 + (lane >> 2);
    int ksl = (lane & 3) * 8;
    const ushort* b0 = bt3 + (long)r0 * 2048 + ks0 + ksl;
    const ushort* b1 = bt3 + (long)r1 * 2048 + ks0 + ksl;
    ushort* lB0 = &Bs[(wave * 2 + 0) * 16][0];
    ushort* lB1 = &Bs[(wave * 2 + 1) * 16][0];

    float4v acc[4][4] = {};

    for (int k0 = 0; k0 < 512; k0 += 32) {
        dma16(b0 + k0, lB0);
        dma16(b1 + k0, lB1);
#pragma unroll
        for (int it = 0; it < 2; ++it) {
            int r = srow + it * 64;
            long row = row0 + r;
            int l = (int)(row & (LSEQ - 1));
            int cch = ks0 + k0 + sseg * 8;
            short8 v[4];
#pragma unroll
            for (int t = 0; t < 4; ++t) {
                if (l - 3 + t >= 0) v[t] = *(const short8*)&xz[(row - 3 + t) * 4096 + cch];
                else { short8 zz = {0,0,0,0,0,0,0,0}; v[t] = zz; }
            }
            ushort o[8];
#pragma unroll
            for (int j = 0; j < 8; ++j) {
                float4 w = ((const float4*)cw)[cch + j];
                float a = cb[cch + j]
                        + bf2f((ushort)v[0][j]) * w.x + bf2f((ushort)v[1][j]) * w.y
                        + bf2f((ushort)v[2][j]) * w.z + bf2f((ushort)v[3][j]) * w.w;
                a = a / (1.f + __expf(-a));
                o[j] = f2bf(a);
            }
            *(short8*)&As[r][sseg * 8] = *(const short8*)o;
        }
        __syncthreads();

        short8 afrag[4], bfrag[4];
#pragma unroll
        for (int i = 0; i < 4; ++i)
            afrag[i] = *reinterpret_cast<const short8*>(&As[wm * 64 + i * 16 + l16][quad * 8]);
#pragma unroll
        for (int j = 0; j < 4; ++j)
            bfrag[j] = *reinterpret_cast<const short8*>(&Bs[wn * 64 + j * 16 + l16][quad * 8]);
#pragma unroll
        for (int i = 0; i < 4; ++i)
#pragma unroll
            for (int j = 0; j < 4; ++j)
                acc[i][j] = __builtin_amdgcn_mfma_f32_16x16x32_bf16(
                    afrag[i], bfrag[j], acc[i][j], 0, 0, 0);
        __syncthreads();
    }
#pragma unroll
    for (int i = 0; i < 4; ++i) {
#pragma unroll
        for (int j = 0; j < 4; ++j) {
            int rbase = row0 + wm * 64 + i * 16 + quad * 4;
            int c = wn * 64 + j * 16 + l16;
            if (c < 96) {
#pragma unroll
                for (int r = 0; r < 4; ++r)
                    atomicAdd(&dbc[(long)(rbase + r) * 96 + c], acc[i][j][r]);
            }
        }
    }
}

// ---------------- VALU-staged MFMA GEMM for dt (A fp32, K=64) ----------------
__global__ __launch_bounds__(256)
void mfma_gemm_dt(const float* __restrict__ A, int lda,
                  const ushort* __restrict__ Bt, int ldbt,
                  ushort* __restrict__ C, int ldc, int K,
                  const float* __restrict__ aux) {
    __shared__ __align__(16) ushort As[128][40];
    __shared__ __align__(16) ushort Bs[128][40];
    int tid = threadIdx.x;
    int wave = tid >> 6, lane = tid & 63;
    int wm = wave >> 1, wn = wave & 1;
    int quad = lane >> 4, l16 = lane & 15;
    int row0 = blockIdx.y * 128, col0 = blockIdx.x * 128;
    int srow = tid >> 2, sseg = tid & 3;

    float4v acc[4][4] = {};

    for (int k0 = 0; k0 < K; k0 += 32) {
#pragma unroll
        for (int it = 0; it < 2; ++it) {
            int r = srow + it * 64;
            const float* ap = A + (long)(row0 + r) * lda + k0 + sseg * 8;
            ushort tmp[8];
#pragma unroll
            for (int j = 0; j < 8; ++j) tmp[j] = f2bf(ap[j]);
            *reinterpret_cast<short8*>(&As[r][sseg * 8]) =
                *reinterpret_cast<const short8*>(tmp);
            const ushort* bp = Bt + (long)(col0 + r) * ldbt + k0 + sseg * 8;
            *reinterpret_cast<short8*>(&Bs[r][sseg * 8]) =
                *reinterpret_cast<const short8*>(bp);
        }
        __syncthreads();
        short8 afrag[4], bfrag[4];
#pragma unroll
        for (int i = 0; i < 4; ++i)
            afrag[i] = *reinterpret_cast<const short8*>(&As[wm * 64 + i * 16 + l16][quad * 8]);
#pragma unroll
        for (int j = 0; j < 4; ++j)
            bfrag[j] = *reinterpret_cast<const short8*>(&Bs[wn * 64 + j * 16 + l16][quad * 8]);
#pragma unroll
        for (int i = 0; i < 4; ++i)
#pragma unroll
            for (int j = 0; j < 4; ++j)
                acc[i][j] = __builtin_amdgcn_mfma_f32_16x16x32_bf16(
                    afrag[i], bfrag[j], acc[i][j], 0, 0, 0);
        __syncthreads();
    }
#pragma unroll
    for (int i = 0; i < 4; ++i) {
#pragma unroll
        for (int j = 0; j < 4; ++j) {
            int rbase = row0 + wm * 64 + i * 16 + quad * 4;
            int c = col0 + wn * 64 + j * 16 + l16;
#pragma unroll
            for (int r = 0; r < 4; ++r) {
                float v = acc[i][j][r] + aux[c];
                v = (v > 20.f) ? v : __logf(1.f + __expf(v));
                C[(long)(rbase + r) * ldc + c] = f2bf(v);
            }
        }
    }
}

// ---------------- chunked selective scan, conv fused -----------------------
// thread = (b,c); 32 chunks of 64. A2[s] = A*log2(e); decay = v_exp(d*A2).
__global__ __launch_bounds__(256)
void scan_part1(const ushort* __restrict__ xz,     // xi at row*4096 + c
                const ushort* __restrict__ dlt,    // delta [8192][2048]
                const float* __restrict__ dbc,     // [ROWS][96]: dt|B|C
                const float* __restrict__ A_log,
                const float* __restrict__ cw, const float* __restrict__ cb,
                float* __restrict__ hbuf,          // [B][G][16][2048]
                float* __restrict__ sdbuf) {       // [B][G][2048]
    int c = blockIdx.y * 256 + threadIdx.x;
    int b = blockIdx.z, g = blockIdx.x;
    float A2[16];
#pragma unroll
    for (int s = 0; s < 16; ++s) A2[s] = -__expf(A_log[c * 16 + s]) * LOG2E;
    float4 w = ((const float4*)cw)[c];
    float cbc = cb[c];
    float h[16] = {};
    float sumd = 0.f;
    long row0 = (long)b * LSEQ + (long)g * LCHUNK;
    int l0 = g * LCHUNK;
    float x0 = (l0 >= 3) ? bf2f(xz[(row0 - 3) * 4096 + c]) : 0.f;
    float x1 = (l0 >= 2) ? bf2f(xz[(row0 - 2) * 4096 + c]) : 0.f;
    float x2 = (l0 >= 1) ? bf2f(xz[(row0 - 1) * 4096 + c]) : 0.f;
    long row = row0;
    for (int l = 0; l < LCHUNK; ++l, ++row) {
        float x3 = bf2f(xz[row * 4096 + c]);
        float xc = cbc + x0 * w.x + x1 * w.y + x2 * w.z + x3 * w.w;
        xc = xc / (1.f + __expf(-xc));
        x0 = x1; x1 = x2; x2 = x3;
        float d = bf2f(dlt[row * 2048 + c]);
        const float* __restrict__ bc = dbc + row * 96;
        sumd += d;
        float dx = d * xc;
#pragma unroll
        for (int s = 0; s < 16; ++s)
            h[s] = fexp2(d * A2[s]) * h[s] + dx * bc[64 + s];
    }
    long hb = ((long)(b * NCHUNK + g) * 16) * 2048 + c;
#pragma unroll
    for (int s = 0; s < 16; ++s) hbuf[hb + (long)s * 2048] = h[s];
    sdbuf[(long)(b * NCHUNK + g) * 2048 + c] = sumd;
}

// part2: serial combine over chunks; hbuf becomes h_in per chunk.
__global__ __launch_bounds__(256)
void scan_part2(float* __restrict__ hbuf, const float* __restrict__ sdbuf,
                const float* __restrict__ A_log) {
    int gl = blockIdx.x * 256 + threadIdx.x;   // 131072 threads
    int c = gl & 2047, s = (gl >> 11) & 15, b = gl >> 15;
    float A2 = -__expf(A_log[c * 16 + s]) * LOG2E;
    float hrun = 0.f;
    for (int g = 0; g < NCHUNK; ++g) {
        long hi = ((long)(b * NCHUNK + g) * 16 + s) * 2048 + c;
        float hout = hbuf[hi];
        float sd = sdbuf[(long)(b * NCHUNK + g) * 2048 + c];
        hbuf[hi] = hrun;
        hrun = fexp2(A2 * sd) * hrun + hout;
    }
}

// part3: re-scan from h_in; y = sum_s h*C; D-skip + SiLU gate; y -> dlt (bf16).
__global__ __launch_bounds__(256)
void scan_part3(const ushort* __restrict__ xz,    // xi + z halves (read-only)
                ushort* __restrict__ dlt,         // delta in / gated y out
                const float* __restrict__ dbc,
                const float* __restrict__ A_log,
                const float* __restrict__ cw, const float* __restrict__ cb,
                const float* __restrict__ Dp,
                const float* __restrict__ hbuf) {
    int c = blockIdx.y * 256 + threadIdx.x;
    int b = blockIdx.z, g = blockIdx.x;
    float A2[16], h[16];
#pragma unroll
    for (int s = 0; s < 16; ++s) A2[s] = -__expf(A_log[c * 16 + s]) * LOG2E;
    long hb = ((long)(b * NCHUNK + g) * 16) * 2048 + c;
#pragma unroll
    for (int s = 0; s < 16; ++s) h[s] = hbuf[hb + (long)s * 2048];
    float4 w = ((const float4*)cw)[c];
    float cbc = cb[c];
    float Dc = Dp[c];
    long row0 = (long)b * LSEQ + (long)g * LCHUNK;
    int l0 = g * LCHUNK;
    float x0 = (l0 >= 3) ? bf2f(xz[(row0 - 3) * 4096 + c]) : 0.f;
    float x1 = (l0 >= 2) ? bf2f(xz[(row0 - 2) * 4096 + c]) : 0.f;
    float x2 = (l0 >= 1) ? bf2f(xz[(row0 - 1) * 4096 + c]) : 0.f;
    long row = row0;
    for (int l = 0; l < LCHUNK; ++l, ++row) {
        float x3 = bf2f(xz[row * 4096 + c]);
        float xc = cbc + x0 * w.x + x1 * w.y + x2 * w.z + x3 * w.w;
        xc = xc / (1.f + __expf(-xc));
        x0 = x1; x1 = x2; x2 = x3;
        float d = bf2f(dlt[row * 2048 + c]);
        float z = bf2f(xz[row * 4096 + 2048 + c]);
        const float* __restrict__ bc = dbc + row * 96;
        float dx = d * xc;
        float y = 0.f;
#pragma unroll
        for (int s = 0; s < 16; ++s) {
            h[s] = fexp2(d * A2[s]) * h[s] + dx * bc[64 + s];
            y += h[s] * bc[80 + s];
        }
        float yv = (y + xc * Dc) * (z / (1.f + __expf(-z)));
        dlt[row * 2048 + c] = f2bf(yv);
    }
}

extern "C" void kernel_launch(void* const* d_in, const int* in_sizes, int n_in,
                              void* d_out, int out_size, void* d_ws, size_t ws_size,
                              hipStream_t stream) {
    const float* x        = (const float*)d_in[0];
    const float* rms_w    = (const float*)d_in[1];
    const float* in_proj  = (const float*)d_in[2];
    const float* conv_w   = (const float*)d_in[3];
    const float* conv_b   = (const float*)d_in[4];
    const float* x_proj   = (const float*)d_in[5];
    const float* dt_w     = (const float*)d_in[6];
    const float* dt_b     = (const float*)d_in[7];
    const float* A_log    = (const float*)d_in[8];
    const float* Dp       = (const float*)d_in[9];
    const float* out_proj = (const float*)d_in[10];
    float* out = (float*)d_out;

    char* p = (char*)d_ws;
    ushort* xz  = (ushort*)p;   p += (size_t)ROWS * 4096 * 2;   // 64 MB  xi|z
    ushort* dlt = (ushort*)p;   p += (size_t)ROWS * 2048 * 2;   // 32 MB  delta -> gated y
    float*  dbc = (float*)p;    p += (size_t)ROWS * 96 * 4;     // 3 MB
    ushort* bt1 = (ushort*)p;   p += (size_t)4096 * 1024 * 2;   // 8 MB   in_proj^T
    ushort* bt2 = (ushort*)p;   p += (size_t)1024 * 2048 * 2;   // 4 MB   out_proj^T
    ushort* bt3 = (ushort*)p;   p += (size_t)128 * 2048 * 2;    // 512 KB x_proj^T (96 rows valid)
    ushort* bt4 = (ushort*)p;   p += (size_t)2048 * 64 * 2;     // 256 KB dt_w^T
    ushort* xn  = (ushort*)p;   p += (size_t)ROWS * 1024 * 2;   // 16.78 MB (dead after in_proj)
    float* sdbuf = (float*)p;   p += (size_t)4 * NCHUNK * 2048 * 4; // 1 MB
    float* hbuf  = (float*)xn;  // 4*32*16*2048*4 = 16.78 MB, overlays xn exactly
    // total ~129 MiB

    // 1. prep: weight transposes + RMSNorm -> xn bf16 + dbc zero
    prep_kernel<<<15424, 256, 0, stream>>>(in_proj, bt1, out_proj, bt2,
                                           x_proj, bt3, dt_w, bt4,
                                           x, rms_w, xn, dbc);
    // 2. xz = xn @ in_proj  [8192,1024]@[1024,4096] -> bf16
    //    256x256, 8 waves (2x4), BK=64 quadrant phases: grid 16x32, NT=16.
    gemm_ring<2, 4, 8, 4, 0><<<dim3(4096 / 256, ROWS / 256), 512, 0, stream>>>(
        xn, DIM, bt1, 1024, xz, 4096, DIM, nullptr);
    // 3. dbc += silu(conv(xi)) @ x_proj  (fused conv, split-K x4, atomics)
    xproj_conv_gemm<<<dim3(4, ROWS / 128), 256, 0, stream>>>(
        xz, conv_w, conv_b, bt3, dbc);
    // 4. dlt = softplus(dbc[:,:64] @ dt_w + dt_b) -> bf16
    mfma_gemm_dt<<<dim3(2048 / 128, ROWS / 128), 256, 0, stream>>>(
        dbc, 96, bt4, 64, dlt, 2048, DTRANK, dt_b);
    // 5-7. chunked selective scan (conv recomputed via rolling window)
    scan_part1<<<dim3(NCHUNK, DINNER / 256, 4), 256, 0, stream>>>(
        xz, dlt, dbc, A_log, conv_w, conv_b, hbuf, sdbuf);
    scan_part2<<<512, 256, 0, stream>>>(hbuf, sdbuf, A_log);
    scan_part3<<<dim3(NCHUNK, DINNER / 256, 4), 256, 0, stream>>>(
        xz, dlt, dbc, A_log, conv_w, conv_b, Dp, hbuf);
    // 8. out = x + y @ out_proj  [8192,2048]@[2048,1024] -> f32 (residual)
    //    256x128, 8 waves (4x2), BK=64 quadrant phases: grid 8x32, NT=32.
    gemm_ring<4, 2, 4, 4, 2><<<dim3(DIM / 128, ROWS / 256), 512, 0, stream>>>(
        dlt, DINNER, bt2, DINNER, out, DIM, DINNER, x);
}

// Round 10
// 465.607 us; speedup vs baseline: 1.0770x; 1.0236x over previous
//
#include <hip/hip_runtime.h>
#include <hip/hip_bf16.h>
#include <math.h>

// Mamba block. 8 launches: prep(transposes+rmsnorm+zero) | in_proj gemm |
// x_proj pipelined conv-GEMM (split-K, atomicAdd) | dt gemm |
// scan part1/2/3 (conv fused via rolling window, 32 chunks) | out_proj gemm.
// Dims fixed: B=4, L=2048, dim=1024, d_inner=2048, d_state=16, d_conv=4,
// dt_rank=64. Rows = B*L = 8192.
//
// GEMMs: round-8 quadrant-phase build (best measured 476.6 us; 8 schedule
// variants confirm the plain-HIP plateau — no further GEMM work).
// THIS ROUND: xproj_conv_gemm rewritten as a software-pipelined
// double-buffer. Old: [128][32] LDS (8-way read conflicts) + 2 barriers/
// K-step with ALL conv VALU + tap loads serialized between them (no
// cross-wave VALU/MFMA overlap). New: fragment-major LDS both operands
// (0 conflicts), ONE barrier/K-step, staging of tile t+1 (dma B + tap
// loads issued pre-MFMA, conv VALU + ds_write post-MFMA into the other
// buffer) overlapped with tile t's MFMA via wave skew (T14 prereqs met:
// reg-staged path + real compute phase).

#define ROWS 8192
#define DIM 1024
#define DINNER 2048
#define DSTATE 16
#define DTRANK 64
#define LSEQ 2048
#define NCHUNK 32
#define LCHUNK 64    // LSEQ/NCHUNK

#define LOG2E 1.4426950408889634f

typedef unsigned short ushort;
typedef __attribute__((ext_vector_type(8))) short short8;
typedef __attribute__((ext_vector_type(4))) float float4v;

__device__ inline ushort f2bf(float f) {
    __hip_bfloat16 h = __float2bfloat16(f);
    return *reinterpret_cast<ushort*>(&h);
}
__device__ inline float bf2f(ushort u) {
    union { unsigned int i; float f; } w; w.i = ((unsigned int)u) << 16; return w.f;
}

// raw v_exp_f32 (2^x), single instruction. NOT libm exp2f (precise, ~6 instr).
__device__ inline float fexp2(float x) {
#if __has_builtin(__builtin_amdgcn_exp2f)
    return __builtin_amdgcn_exp2f(x);
#else
    return __expf(x * 0.69314718056f);
#endif
}

// async global->LDS DMA, 16 B/lane. lds dest = wave-uniform base + lane*16.
__device__ inline void dma16(const void* g, void* l) {
    __builtin_amdgcn_global_load_lds(
        (const __attribute__((address_space(1))) unsigned int*)g,
        (__attribute__((address_space(3))) unsigned int*)l, 16, 0, 0);
}

// counted vmcnt wait with literal N (compiler fence via "memory")
template <int N> __device__ inline void vwait() {
    if constexpr (N == 0)      asm volatile("s_waitcnt vmcnt(0)" ::: "memory");
    else if constexpr (N == 6) asm volatile("s_waitcnt vmcnt(6)" ::: "memory");
    else if constexpr (N == 8) asm volatile("s_waitcnt vmcnt(8)" ::: "memory");
    else static_assert(N < 0, "unsupported vmcnt literal");
}

__device__ inline void phase_sync_pre() {
    __builtin_amdgcn_s_barrier();
    asm volatile("s_waitcnt lgkmcnt(0)" ::: "memory");
    __builtin_amdgcn_sched_barrier(0);
    __builtin_amdgcn_s_setprio(1);
}
__device__ inline void phase_sync_post() {
    __builtin_amdgcn_s_setprio(0);
    __builtin_amdgcn_s_barrier();
}

// ---------------- fused prep: 4 transposes + RMSNorm + dbc zero ------------
__global__ __launch_bounds__(256)
void prep_kernel(const float* __restrict__ in_proj, ushort* __restrict__ bt1,
                 const float* __restrict__ out_proj, ushort* __restrict__ bt2,
                 const float* __restrict__ x_proj, ushort* __restrict__ bt3,
                 const float* __restrict__ dt_w, ushort* __restrict__ bt4,
                 const float* __restrict__ x, const float* __restrict__ rms_w,
                 ushort* __restrict__ xn, float* __restrict__ dbc) {
    __shared__ float tld[32][33];
    __shared__ float red[4];
    int bid = blockIdx.x, tid = threadIdx.x;
    if (bid < 6464) {
        const float* in; ushort* outT; int R, C, bx, by;
        if (bid < 4096)      { in = in_proj;  outT = bt1; R = 1024; C = 4096; bx = bid & 127; by = bid >> 7; }
        else if (bid < 6144) { int t = bid - 4096; in = out_proj; outT = bt2; R = 2048; C = 1024; bx = t & 31; by = t >> 5; }
        else if (bid < 6336) { int t = bid - 6144; in = x_proj;  outT = bt3; R = 2048; C = 96;  bx = t % 3;  by = t / 3; }
        else                 { int t = bid - 6336; in = dt_w;    outT = bt4; R = 64;   C = 2048; bx = t & 63; by = t >> 6; }
        int tx = tid & 31, ty = tid >> 5;
#pragma unroll
        for (int k = 0; k < 4; ++k)
            tld[ty + k * 8][tx] = in[(long)(by * 32 + ty + k * 8) * C + bx * 32 + tx];
        __syncthreads();
#pragma unroll
        for (int k = 0; k < 4; ++k)
            outT[(long)(bx * 32 + ty + k * 8) * R + by * 32 + tx] = f2bf(tld[tx][ty + k * 8]);
    } else if (bid < 14656) {
        int row = bid - 6464;
        float4 xv = ((const float4*)(x + (long)row * DIM))[tid];
        float ss = xv.x * xv.x + xv.y * xv.y + xv.z * xv.z + xv.w * xv.w;
        for (int off = 32; off > 0; off >>= 1) ss += __shfl_down(ss, off);
        if ((tid & 63) == 0) red[tid >> 6] = ss;
        __syncthreads();
        float scale = rsqrtf((red[0] + red[1] + red[2] + red[3]) / DIM + 1e-5f);
        float4 wv = ((const float4*)rms_w)[tid];
        ushort4 ov;
        ov.x = f2bf(xv.x * scale * wv.x);
        ov.y = f2bf(xv.y * scale * wv.y);
        ov.z = f2bf(xv.z * scale * wv.z);
        ov.w = f2bf(xv.w * scale * wv.w);
        ((ushort4*)xn)[(long)row * 256 + tid] = ov;
    } else {
        int idx = (bid - 14656) * 256 + tid;
        float4 z = {0.f, 0.f, 0.f, 0.f};
        ((float4*)dbc)[idx] = z;   // 768*256*4 = 786432 floats
    }
}

// ---------- BK=64 double-buffer quadrant-phase fragment-major GEMM ----------
// MW x NW waves; per-wave output (MF*16) x (NF*16). MH=MF/2, NH=NF/2.
// LDS buffer: A frags [(BLKM/16) groups x 2 khalves x 1KiB] then B likewise.
// Per K-tile t (buf t&1), 4 phases (quadrants over full K=64):
//  P1: read A-set0(MH*2) + B-set0(NH*2)          -> MFMA Q(lo m, lo n)
//  P2: read B-set1(NH*2)                          -> MFMA Q(lo m, hi n)
//  P3: read A-set1(MH*2); stage B frags of t+2    -> MFMA Q(hi m, hi n)
//  P4: stage A frags of t+2                       -> MFMA Q(hi m, lo n)
// Iter end: vmcnt(DPT) [t+2 in flight, t+1 landed] + barrier.
// EPI: 0 = bf16 store; 2 = acc + aux[row*ldc+col] -> f32 (residual).
template <int MW, int NW, int MF, int NF, int EPI>
__global__ __launch_bounds__(MW * NW * 64, 2)
void gemm_ring(const ushort* __restrict__ A, int lda,
               const ushort* __restrict__ Bt, int ldbt,
               void* __restrict__ Cv, int ldc, int K,
               const float* __restrict__ aux) {
    constexpr int W    = MW * NW;             // waves per block (8)
    constexpr int BLKM = MW * MF * 16;
    constexpr int BLKN = NW * NF * 16;
    constexpr int TILE = (BLKM + BLKN) * 64;  // ushorts per buffer
    constexpr int NAf  = BLKM / (8 * W);      // A frags staged per wave
    constexpr int NBf  = BLKN / (8 * W);      // B frags staged per wave
    constexpr int DPT  = NAf + NBf;           // dmas per wave per K-tile
    constexpr int MH   = MF / 2;
    constexpr int NH   = NF / 2;
    __shared__ __align__(16) ushort lds[2 * TILE];

    const int tid  = threadIdx.x;
    const int w    = tid >> 6, lane = tid & 63;
    const int wm   = w / NW,   wn   = w % NW;
    const int quad = lane >> 4, l16 = lane & 15;
    const long row0 = (long)blockIdx.y * BLKM;
    const long col0 = (long)blockIdx.x * BLKN;

    // per-lane global srcs in fragment order: frag f=(g,h): row g*16+l16,
    // k offset h*32 + quad*8. Wave w stages frags {w + i*W}.
    const ushort* gA[NAf];
    const ushort* gB[NBf];
#pragma unroll
    for (int i = 0; i < NAf; ++i) {
        int f = w + i * W;
        gA[i] = A + (row0 + (f >> 1) * 16 + l16) * lda + (f & 1) * 32 + quad * 8;
    }
#pragma unroll
    for (int i = 0; i < NBf; ++i) {
        int f = w + i * W;
        gB[i] = Bt + (col0 + (f >> 1) * 16 + l16) * ldbt + (f & 1) * 32 + quad * 8;
    }

    const int NT = K >> 6;                    // K-tiles of 64
    float4v acc[MF][NF] = {};

    auto stageA = [&](int kt) {
        ushort* lb = lds + (kt & 1) * TILE;
        const int ko = kt << 6;
#pragma unroll
        for (int i = 0; i < NAf; ++i)
            dma16(gA[i] + ko, lb + (w + i * W) * 512);
    };
    auto stageB = [&](int kt) {
        ushort* lb = lds + (kt & 1) * TILE + BLKM * 64;
        const int ko = kt << 6;
#pragma unroll
        for (int i = 0; i < NBf; ++i)
            dma16(gB[i] + ko, lb + (w + i * W) * 512);
    };

    // prologue: tiles 0,1 staged; tile 0 landed (tile 1's DPT may remain)
    stageB(0); stageA(0); stageB(1); stageA(1);
    vwait<DPT>();
    __builtin_amdgcn_s_barrier();

    for (int t = 0; t < NT; ++t) {
        const ushort* lb  = lds + (t & 1) * TILE;
        const ushort* lbB = lb + BLKM * 64;
        const bool stg = (t + 2 < NT);
        short8 A0[MH][2], A1[MH][2], B0[NH][2], B1[NH][2];

        // ---- P1: A-set0 + B-set0 -> Q(lo,lo) ----
#pragma unroll
        for (int m = 0; m < MH; ++m)
#pragma unroll
            for (int h = 0; h < 2; ++h)
                A0[m][h] = *reinterpret_cast<const short8*>(
                    &lb[((wm * MF + m) * 2 + h) * 512 + lane * 8]);
#pragma unroll
        for (int n = 0; n < NH; ++n)
#pragma unroll
            for (int h = 0; h < 2; ++h)
                B0[n][h] = *reinterpret_cast<const short8*>(
                    &lbB[((wn * NF + n) * 2 + h) * 512 + lane * 8]);
        phase_sync_pre();
#pragma unroll
        for (int m = 0; m < MH; ++m)
#pragma unroll
            for (int n = 0; n < NH; ++n)
#pragma unroll
                for (int h = 0; h < 2; ++h)
                    acc[m][n] = __builtin_amdgcn_mfma_f32_16x16x32_bf16(
                        A0[m][h], B0[n][h], acc[m][n], 0, 0, 0);
        phase_sync_post();

        // ---- P2: B-set1 -> Q(lo,hi) ----
#pragma unroll
        for (int n = 0; n < NH; ++n)
#pragma unroll
            for (int h = 0; h < 2; ++h)
                B1[n][h] = *reinterpret_cast<const short8*>(
                    &lbB[((wn * NF + NH + n) * 2 + h) * 512 + lane * 8]);
        phase_sync_pre();
#pragma unroll
        for (int m = 0; m < MH; ++m)
#pragma unroll
            for (int n = 0; n < NH; ++n)
#pragma unroll
                for (int h = 0; h < 2; ++h)
                    acc[m][NH + n] = __builtin_amdgcn_mfma_f32_16x16x32_bf16(
                        A0[m][h], B1[n][h], acc[m][NH + n], 0, 0, 0);
        phase_sync_post();

        // ---- P3: A-set1; stage B(t+2) [B reads retired at P2 post-bar] ----
#pragma unroll
        for (int m = 0; m < MH; ++m)
#pragma unroll
            for (int h = 0; h < 2; ++h)
                A1[m][h] = *reinterpret_cast<const short8*>(
                    &lb[((wm * MF + MH + m) * 2 + h) * 512 + lane * 8]);
        if (stg) stageB(t + 2);
        phase_sync_pre();
#pragma unroll
        for (int m = 0; m < MH; ++m)
#pragma unroll
            for (int n = 0; n < NH; ++n)
#pragma unroll
                for (int h = 0; h < 2; ++h)
                    acc[MH + m][NH + n] = __builtin_amdgcn_mfma_f32_16x16x32_bf16(
                        A1[m][h], B1[n][h], acc[MH + m][NH + n], 0, 0, 0);
        phase_sync_post();

        // ---- P4: stage A(t+2) [A reads retired at P3 post-bar] ----
        if (stg) stageA(t + 2);
        phase_sync_pre();
#pragma unroll
        for (int m = 0; m < MH; ++m)
#pragma unroll
            for (int n = 0; n < NH; ++n)
#pragma unroll
                for (int h = 0; h < 2; ++h)
                    acc[MH + m][n] = __builtin_amdgcn_mfma_f32_16x16x32_bf16(
                        A1[m][h], B0[n][h], acc[MH + m][n], 0, 0, 0);
        __builtin_amdgcn_s_setprio(0);

        // iteration end: t+1 must be landed before next iter's reads
        if (stg) vwait<DPT>(); else vwait<0>();
        if (t < NT - 1) __builtin_amdgcn_s_barrier();
    }

#pragma unroll
    for (int m = 0; m < MF; ++m) {
#pragma unroll
        for (int n = 0; n < NF; ++n) {
            long rbase = row0 + wm * (MF * 16) + m * 16 + quad * 4;
            long c = col0 + wn * (NF * 16) + n * 16 + l16;
#pragma unroll
            for (int r = 0; r < 4; ++r) {
                float v = acc[m][n][r];
                long idx = (rbase + r) * (long)ldc + c;
                if (EPI == 2) ((float*)Cv)[idx] = v + aux[idx];
                else          ((ushort*)Cv)[idx] = f2bf(v);
            }
        }
    }
}

// ------- x_proj pipelined conv-GEMM, split-K, fragment-major ----------------
// 128x128 tile per block (col pad to 128, write-guard c<96), 4 waves.
// Double-buffered BK=32; per K-step: {dma B(t+1); issue tap loads(t+1);
// ds_read frags(t); lgkm(0); MFMA(t)x16; conv-VALU(t+1)+ds_write->buf^1;
// vmcnt(0); lgkm(0); barrier}. One barrier/K-step; staging overlaps MFMA
// via wave skew. Fragment-major LDS: frag f = 512 ushorts at f*512, lane l
// slot l*8 (16B) -> zero-conflict ds_read/ds_write; B staged by dma16 with
// per-lane pre-permuted src (row l16, kseg quad).
__global__ __launch_bounds__(256)
void xproj_conv_gemm(const ushort* __restrict__ xz,
                     const float* __restrict__ cw, const float* __restrict__ cb,
                     const ushort* __restrict__ bt3,   // [128][2048]
                     float* __restrict__ dbc) {
    __shared__ __align__(16) ushort lds[2 * 16 * 512];  // 32 KiB
    int tid = threadIdx.x;
    int wave = tid >> 6, lane = tid & 63;
    int wm = wave >> 1, wn = wave & 1;
    int quad = lane >> 4, l16 = lane & 15;
    int row0 = blockIdx.y * 128;
    int ks0 = blockIdx.x * 512;

    // staging identity: thread -> (frag f = (tid>>6)+it*4, slot s = tid&63)
    int sf = tid >> 6;
    int ss = tid & 63;
    int srow = ss & 15;          // row within frag
    int sq = ss >> 4;            // k-quad (ch offset sq*8)

    // B dma srcs: wave stages frags {wave*2, wave*2+1}
    const ushort* b0 = bt3 + (long)((wave * 2 + 0) * 16 + l16) * 2048 + ks0 + quad * 8;
    const ushort* b1 = bt3 + (long)((wave * 2 + 1) * 16 + l16) * 2048 + ks0 + quad * 8;

    float4v acc[4][4] = {};
    short8 tv[2][4];             // taps for next tile (2 its x 4 taps)

    auto stageB = [&](int k0, int buf) {
        ushort* Bb = lds + buf * 16 * 512 + 8 * 512;
        dma16(b0 + k0, Bb + (wave * 2 + 0) * 512);
        dma16(b1 + k0, Bb + (wave * 2 + 1) * 512);
    };
    auto conv_load = [&](int k0) {
#pragma unroll
        for (int it = 0; it < 2; ++it) {
            int f = sf + it * 4;
            long row = row0 + f * 16 + srow;
            int l = (int)(row & (LSEQ - 1));
            int cch = ks0 + k0 + sq * 8;
#pragma unroll
            for (int t = 0; t < 4; ++t) {
                if (l - 3 + t >= 0)
                    tv[it][t] = *(const short8*)&xz[(row - 3 + t) * 4096 + cch];
                else { short8 zz = {0,0,0,0,0,0,0,0}; tv[it][t] = zz; }
            }
        }
    };
    auto conv_compute_write = [&](int k0, int buf) {
        ushort* Ab = lds + buf * 16 * 512;
#pragma unroll
        for (int it = 0; it < 2; ++it) {
            int f = sf + it * 4;
            int cch = ks0 + k0 + sq * 8;
            ushort o[8];
#pragma unroll
            for (int j = 0; j < 8; ++j) {
                float4 w = ((const float4*)cw)[cch + j];
                float a = cb[cch + j]
                        + bf2f((ushort)tv[it][0][j]) * w.x
                        + bf2f((ushort)tv[it][1][j]) * w.y
                        + bf2f((ushort)tv[it][2][j]) * w.z
                        + bf2f((ushort)tv[it][3][j]) * w.w;
                a = a / (1.f + __expf(-a));
                o[j] = f2bf(a);
            }
            *(short8*)&Ab[(f * 64 + ss) * 8] = *(const short8*)o;
        }
    };

    // prologue: stage tile 0 (A via conv, B via dma)
    stageB(0, 0);
    conv_load(0);
    conv_compute_write(0, 0);
    vwait<0>();
    asm volatile("s_waitcnt lgkmcnt(0)" ::: "memory");
    __builtin_amdgcn_s_barrier();

    for (int k0 = 0; k0 < 512; k0 += 32) {
        const int cur = (k0 >> 5) & 1;
        const bool nxt = (k0 + 32 < 512);
        if (nxt) { stageB(k0 + 32, cur ^ 1); conv_load(k0 + 32); }

        const ushort* Ab = lds + cur * 16 * 512;
        const ushort* Bb = Ab + 8 * 512;
        short8 afrag[4], bfrag[4];
#pragma unroll
        for (int i = 0; i < 4; ++i)
            afrag[i] = *(const short8*)&Ab[((wm * 4 + i) * 64 + lane) * 8];
#pragma unroll
        for (int j = 0; j < 4; ++j)
            bfrag[j] = *(const short8*)&Bb[((wn * 4 + j) * 64 + lane) * 8];
        asm volatile("s_waitcnt lgkmcnt(0)" ::: "memory");
        __builtin_amdgcn_sched_barrier(0);
        __builtin_amdgcn_s_setprio(1);
#pragma unroll
        for (int i = 0; i < 4; ++i)
#pragma unroll
            for (int j = 0; j < 4; ++j)
                acc[i][j] = __builtin_amdgcn_mfma_f32_16x16x32_bf16(
                    afrag[i], bfrag[j], acc[i][j], 0, 0, 0);
        __builtin_amdgcn_s_setprio(0);

        if (nxt) conv_compute_write(k0 + 32, cur ^ 1);  // into other buffer
        vwait<0>();                                     // drain B(t+1) dmas
        asm volatile("s_waitcnt lgkmcnt(0)" ::: "memory"); // ds_writes retired
        __builtin_amdgcn_s_barrier();
    }

#pragma unroll
    for (int i = 0; i < 4; ++i) {
#pragma unroll
        for (int j = 0; j < 4; ++j) {
            int rbase = row0 + wm * 64 + i * 16 + quad * 4;
            int c = wn * 64 + j * 16 + l16;
            if (c < 96) {
#pragma unroll
                for (int r = 0; r < 4; ++r)
                    atomicAdd(&dbc[(long)(rbase + r) * 96 + c], acc[i][j][r]);
            }
        }
    }
}

// ---------------- VALU-staged MFMA GEMM for dt (A fp32, K=64) ----------------
__global__ __launch_bounds__(256)
void mfma_gemm_dt(const float* __restrict__ A, int lda,
                  const ushort* __restrict__ Bt, int ldbt,
                  ushort* __restrict__ C, int ldc, int K,
                  const float* __restrict__ aux) {
    __shared__ __align__(16) ushort As[128][40];
    __shared__ __align__(16) ushort Bs[128][40];
    int tid = threadIdx.x;
    int wave = tid >> 6, lane = tid & 63;
    int wm = wave >> 1, wn = wave & 1;
    int quad = lane >> 4, l16 = lane & 15;
    int row0 = blockIdx.y * 128, col0 = blockIdx.x * 128;
    int srow = tid >> 2, sseg = tid & 3;

    float4v acc[4][4] = {};

    for (int k0 = 0; k0 < K; k0 += 32) {
#pragma unroll
        for (int it = 0; it < 2; ++it) {
            int r = srow + it * 64;
            const float* ap = A + (long)(row0 + r) * lda + k0 + sseg * 8;
            ushort tmp[8];
#pragma unroll
            for (int j = 0; j < 8; ++j) tmp[j] = f2bf(ap[j]);
            *reinterpret_cast<short8*>(&As[r][sseg * 8]) =
                *reinterpret_cast<const short8*>(tmp);
            const ushort* bp = Bt + (long)(col0 + r) * ldbt + k0 + sseg * 8;
            *reinterpret_cast<short8*>(&Bs[r][sseg * 8]) =
                *reinterpret_cast<const short8*>(bp);
        }
        __syncthreads();
        short8 afrag[4], bfrag[4];
#pragma unroll
        for (int i = 0; i < 4; ++i)
            afrag[i] = *reinterpret_cast<const short8*>(&As[wm * 64 + i * 16 + l16][quad * 8]);
#pragma unroll
        for (int j = 0; j < 4; ++j)
            bfrag[j] = *reinterpret_cast<const short8*>(&Bs[wn * 64 + j * 16 + l16][quad * 8]);
#pragma unroll
        for (int i = 0; i < 4; ++i)
#pragma unroll
            for (int j = 0; j < 4; ++j)
                acc[i][j] = __builtin_amdgcn_mfma_f32_16x16x32_bf16(
                    afrag[i], bfrag[j], acc[i][j], 0, 0, 0);
        __syncthreads();
    }
#pragma unroll
    for (int i = 0; i < 4; ++i) {
#pragma unroll
        for (int j = 0; j < 4; ++j) {
            int rbase = row0 + wm * 64 + i * 16 + quad * 4;
            int c = col0 + wn * 64 + j * 16 + l16;
#pragma unroll
            for (int r = 0; r < 4; ++r) {
                float v = acc[i][j][r] + aux[c];
                v = (v > 20.f) ? v : __logf(1.f + __expf(v));
                C[(long)(rbase + r) * ldc + c] = f2bf(v);
            }
        }
    }
}

// ---------------- chunked selective scan, conv fused -----------------------
// thread = (b,c); 32 chunks of 64. A2[s] = A*log2(e); decay = v_exp(d*A2).
__global__ __launch_bounds__(256)
void scan_part1(const ushort* __restrict__ xz,     // xi at row*4096 + c
                const ushort* __restrict__ dlt,    // delta [8192][2048]
                const float* __restrict__ dbc,     // [ROWS][96]: dt|B|C
                const float* __restrict__ A_log,
                const float* __restrict__ cw, const float* __restrict__ cb,
                float* __restrict__ hbuf,          // [B][G][16][2048]
                float* __restrict__ sdbuf) {       // [B][G][2048]
    int c = blockIdx.y * 256 + threadIdx.x;
    int b = blockIdx.z, g = blockIdx.x;
    float A2[16];
#pragma unroll
    for (int s = 0; s < 16; ++s) A2[s] = -__expf(A_log[c * 16 + s]) * LOG2E;
    float4 w = ((const float4*)cw)[c];
    float cbc = cb[c];
    float h[16] = {};
    float sumd = 0.f;
    long row0 = (long)b * LSEQ + (long)g * LCHUNK;
    int l0 = g * LCHUNK;
    float x0 = (l0 >= 3) ? bf2f(xz[(row0 - 3) * 4096 + c]) : 0.f;
    float x1 = (l0 >= 2) ? bf2f(xz[(row0 - 2) * 4096 + c]) : 0.f;
    float x2 = (l0 >= 1) ? bf2f(xz[(row0 - 1) * 4096 + c]) : 0.f;
    long row = row0;
    for (int l = 0; l < LCHUNK; ++l, ++row) {
        float x3 = bf2f(xz[row * 4096 + c]);
        float xc = cbc + x0 * w.x + x1 * w.y + x2 * w.z + x3 * w.w;
        xc = xc / (1.f + __expf(-xc));
        x0 = x1; x1 = x2; x2 = x3;
        float d = bf2f(dlt[row * 2048 + c]);
        const float* __restrict__ bc = dbc + row * 96;
        sumd += d;
        float dx = d * xc;
#pragma unroll
        for (int s = 0; s < 16; ++s)
            h[s] = fexp2(d * A2[s]) * h[s] + dx * bc[64 + s];
    }
    long hb = ((long)(b * NCHUNK + g) * 16) * 2048 + c;
#pragma unroll
    for (int s = 0; s < 16; ++s) hbuf[hb + (long)s * 2048] = h[s];
    sdbuf[(long)(b * NCHUNK + g) * 2048 + c] = sumd;
}

// part2: serial combine over chunks; hbuf becomes h_in per chunk.
__global__ __launch_bounds__(256)
void scan_part2(float* __restrict__ hbuf, const float* __restrict__ sdbuf,
                const float* __restrict__ A_log) {
    int gl = blockIdx.x * 256 + threadIdx.x;   // 131072 threads
    int c = gl & 2047, s = (gl >> 11) & 15, b = gl >> 15;
    float A2 = -__expf(A_log[c * 16 + s]) * LOG2E;
    float hrun = 0.f;
    for (int g = 0; g < NCHUNK; ++g) {
        long hi = ((long)(b * NCHUNK + g) * 16 + s) * 2048 + c;
        float hout = hbuf[hi];
        float sd = sdbuf[(long)(b * NCHUNK + g) * 2048 + c];
        hbuf[hi] = hrun;
        hrun = fexp2(A2 * sd) * hrun + hout;
    }
}

// part3: re-scan from h_in; y = sum_s h*C; D-skip + SiLU gate; y -> dlt (bf16).
__global__ __launch_bounds__(256)
void scan_part3(const ushort* __restrict__ xz,    // xi + z halves (read-only)
                ushort* __restrict__ dlt,         // delta in / gated y out
                const float* __restrict__ dbc,
                const float* __restrict__ A_log,
                const float* __restrict__ cw, const float* __restrict__ cb,
                const float* __restrict__ Dp,
                const float* __restrict__ hbuf) {
    int c = blockIdx.y * 256 + threadIdx.x;
    int b = blockIdx.z, g = blockIdx.x;
    float A2[16], h[16];
#pragma unroll
    for (int s = 0; s < 16; ++s) A2[s] = -__expf(A_log[c * 16 + s]) * LOG2E;
    long hb = ((long)(b * NCHUNK + g) * 16) * 2048 + c;
#pragma unroll
    for (int s = 0; s < 16; ++s) h[s] = hbuf[hb + (long)s * 2048];
    float4 w = ((const float4*)cw)[c];
    float cbc = cb[c];
    float Dc = Dp[c];
    long row0 = (long)b * LSEQ + (long)g * LCHUNK;
    int l0 = g * LCHUNK;
    float x0 = (l0 >= 3) ? bf2f(xz[(row0 - 3) * 4096 + c]) : 0.f;
    float x1 = (l0 >= 2) ? bf2f(xz[(row0 - 2) * 4096 + c]) : 0.f;
    float x2 = (l0 >= 1) ? bf2f(xz[(row0 - 1) * 4096 + c]) : 0.f;
    long row = row0;
    for (int l = 0; l < LCHUNK; ++l, ++row) {
        float x3 = bf2f(xz[row * 4096 + c]);
        float xc = cbc + x0 * w.x + x1 * w.y + x2 * w.z + x3 * w.w;
        xc = xc / (1.f + __expf(-xc));
        x0 = x1; x1 = x2; x2 = x3;
        float d = bf2f(dlt[row * 2048 + c]);
        float z = bf2f(xz[row * 4096 + 2048 + c]);
        const float* __restrict__ bc = dbc + row * 96;
        float dx = d * xc;
        float y = 0.f;
#pragma unroll
        for (int s = 0; s < 16; ++s) {
            h[s] = fexp2(d * A2[s]) * h[s] + dx * bc[64 + s];
            y += h[s] * bc[80 + s];
        }
        float yv = (y + xc * Dc) * (z / (1.f + __expf(-z)));
        dlt[row * 2048 + c] = f2bf(yv);
    }
}

extern "C" void kernel_launch(void* const* d_in, const int* in_sizes, int n_in,
                              void* d_out, int out_size, void* d_ws, size_t ws_size,
                              hipStream_t stream) {
    const float* x        = (const float*)d_in[0];
    const float* rms_w    = (const float*)d_in[1];
    const float* in_proj  = (const float*)d_in[2];
    const float* conv_w   = (const float*)d_in[3];
    const float* conv_b   = (const float*)d_in[4];
    const float* x_proj   = (const float*)d_in[5];
    const float* dt_w     = (const float*)d_in[6];
    const float* dt_b     = (const float*)d_in[7];
    const float* A_log    = (const float*)d_in[8];
    const float* Dp       = (const float*)d_in[9];
    const float* out_proj = (const float*)d_in[10];
    float* out = (float*)d_out;

    char* p = (char*)d_ws;
    ushort* xz  = (ushort*)p;   p += (size_t)ROWS * 4096 * 2;   // 64 MB  xi|z
    ushort* dlt = (ushort*)p;   p += (size_t)ROWS * 2048 * 2;   // 32 MB  delta -> gated y
    float*  dbc = (float*)p;    p += (size_t)ROWS * 96 * 4;     // 3 MB
    ushort* bt1 = (ushort*)p;   p += (size_t)4096 * 1024 * 2;   // 8 MB   in_proj^T
    ushort* bt2 = (ushort*)p;   p += (size_t)1024 * 2048 * 2;   // 4 MB   out_proj^T
    ushort* bt3 = (ushort*)p;   p += (size_t)128 * 2048 * 2;    // 512 KB x_proj^T (96 rows valid)
    ushort* bt4 = (ushort*)p;   p += (size_t)2048 * 64 * 2;     // 256 KB dt_w^T
    ushort* xn  = (ushort*)p;   p += (size_t)ROWS * 1024 * 2;   // 16.78 MB (dead after in_proj)
    float* sdbuf = (float*)p;   p += (size_t)4 * NCHUNK * 2048 * 4; // 1 MB
    float* hbuf  = (float*)xn;  // 4*32*16*2048*4 = 16.78 MB, overlays xn exactly
    // total ~129 MiB

    // 1. prep: weight transposes + RMSNorm -> xn bf16 + dbc zero
    prep_kernel<<<15424, 256, 0, stream>>>(in_proj, bt1, out_proj, bt2,
                                           x_proj, bt3, dt_w, bt4,
                                           x, rms_w, xn, dbc);
    // 2. xz = xn @ in_proj  [8192,1024]@[1024,4096] -> bf16
    //    256x256, 8 waves (2x4), BK=64 quadrant phases: grid 16x32, NT=16.
    gemm_ring<2, 4, 8, 4, 0><<<dim3(4096 / 256, ROWS / 256), 512, 0, stream>>>(
        xn, DIM, bt1, 1024, xz, 4096, DIM, nullptr);
    // 3. dbc += silu(conv(xi)) @ x_proj  (pipelined conv staging, split-K x4,
    //    fragment-major LDS, 1 barrier/K-step, atomics)
    xproj_conv_gemm<<<dim3(4, ROWS / 128), 256, 0, stream>>>(
        xz, conv_w, conv_b, bt3, dbc);
    // 4. dlt = softplus(dbc[:,:64] @ dt_w + dt_b) -> bf16
    mfma_gemm_dt<<<dim3(2048 / 128, ROWS / 128), 256, 0, stream>>>(
        dbc, 96, bt4, 64, dlt, 2048, DTRANK, dt_b);
    // 5-7. chunked selective scan (conv recomputed via rolling window)
    scan_part1<<<dim3(NCHUNK, DINNER / 256, 4), 256, 0, stream>>>(
        xz, dlt, dbc, A_log, conv_w, conv_b, hbuf, sdbuf);
    scan_part2<<<512, 256, 0, stream>>>(hbuf, sdbuf, A_log);
    scan_part3<<<dim3(NCHUNK, DINNER / 256, 4), 256, 0, stream>>>(
        xz, dlt, dbc, A_log, conv_w, conv_b, Dp, hbuf);
    // 8. out = x + y @ out_proj  [8192,2048]@[2048,1024] -> f32 (residual)
    //    256x128, 8 waves (4x2), BK=64 quadrant phases: grid 8x32, NT=32.
    gemm_ring<4, 2, 4, 4, 2><<<dim3(DIM / 128, ROWS / 256), 512, 0, stream>>>(
        dlt, DINNER, bt2, DINNER, out, DIM, DINNER, x);
}